// Round 6
// baseline (436.113 us; speedup 1.0000x reference)
//
#include <hip/hip_runtime.h>

constexpr int N_NODES = 100000;
constexpr int F_IN    = 32;
constexpr int H       = 128;
constexpr int OUT_F   = 200;
constexpr int NEDGES  = 1600000;
constexpr float EPS   = 1e-5f;

constexpr int TILE_BLKS  = (N_NODES + 63) / 64;       // 1563
constexpr int MMT        = 4;                         // r21: tiles per GEMM block
constexpr int MM_BLKS    = (TILE_BLKS + MMT - 1) / MMT;   // 391
constexpr int MMD_BLKS   = MM_BLKS * 2;                   // 782 (64-col halves)
constexpr int AGG_BLKS   = N_NODES / 32;              // 3125 (512 thr, 32 nodes, exact)

// ---- CSR build (r19): two-level LDS-binned. Global atomic RMW w/ return
// measured ~21 G/s device-wide regardless of scope/slicing (r0/r2/r3) ->
// 1.6M atomics == 77us. This build: 1.6M DS atomics + ~76K global atomics.
constexpr int NB     = (N_NODES + 127) / 128;         // 782 buckets of 128 nodes
constexpr int BCAP   = 2560;                          // >=11 sigma above 2048 mean
constexpr int P1_EPT = 16, P1_THR = 512;
constexpr int P1_EPB = P1_THR * P1_EPT;               // 8192 edges/block
constexpr int P1_BLKS = (NEDGES + P1_EPB - 1) / P1_EPB;  // 196
constexpr int WS_BLKS = 40;                           // fused into k_p1 (512 thr)
constexpr int P2_IT  = BCAP / 256;                    // 10
constexpr int WQ_BLKS = NEDGES / 4 / 256;             // 1563

typedef __attribute__((ext_vector_type(8))) short  short8;
typedef __attribute__((ext_vector_type(4))) float  f32x4;
typedef __attribute__((ext_vector_type(2))) float  fv2;

__device__ __forceinline__ void fma4(float4& a, float s, const float4& w) {
  a.x = fmaf(s, w.x, a.x); a.y = fmaf(s, w.y, a.y);
  a.z = fmaf(s, w.z, a.z); a.w = fmaf(s, w.w, a.w);
}

__device__ __forceinline__ unsigned short f2bf(float f) {  // RNE
  union { float f; unsigned u; } v; v.f = f;
  unsigned r = v.u + 0x7fffu + ((v.u >> 16) & 1u);
  return (unsigned short)(r >> 16);
}
__device__ __forceinline__ float bflo(unsigned u) { return __uint_as_float(u << 16); }
__device__ __forceinline__ float bfhi(unsigned u) { return __uint_as_float(u & 0xffff0000u); }
__device__ __forceinline__ unsigned pack2(float lo, float hi) {
  return (unsigned)f2bf(lo) | ((unsigned)f2bf(hi) << 16);
}
__device__ __forceinline__ void st_bf4(unsigned short* p, float4 v) {
  uint2 o; o.x = pack2(v.x, v.y); o.y = pack2(v.z, v.w);
  *(uint2*)p = o;
}

// ---------------- fp8 e4m3fn helpers ----------------
#if __has_builtin(__builtin_amdgcn_cvt_pk_f32_fp8) && __has_builtin(__builtin_amdgcn_cvt_pk_fp8_f32)
#define HAVE_FP8_CVT 1
#endif

#ifndef HAVE_FP8_CVT
__device__ __forceinline__ float fp8_dec1(unsigned b) {
  unsigned s = (b >> 7) & 1u, E = (b >> 3) & 15u, m = b & 7u;
  float v;
  if (E) {
    union { unsigned u; float f; } t;
    t.u = (s << 31) | ((E + 120u) << 23) | (m << 20);
    v = t.f;
  } else {
    v = (s ? -1.f : 1.f) * (float)m * 0.001953125f;
  }
  return v;
}
#endif

template <bool HI>
__device__ __forceinline__ fv2 fp8x2(unsigned u) {
#ifdef HAVE_FP8_CVT
  return __builtin_amdgcn_cvt_pk_f32_fp8((int)u, HI);
#else
  unsigned p = HI ? (u >> 16) : u;
  fv2 r; r.x = fp8_dec1(p & 0xffu); r.y = fp8_dec1((p >> 8) & 0xffu);
  return r;
#endif
}

__device__ __forceinline__ unsigned char f32_to_fp8(float f) {
#ifdef HAVE_FP8_CVT
  return (unsigned char)(__builtin_amdgcn_cvt_pk_fp8_f32(f, f, 0, false) & 0xff);
#else
  union { float f; unsigned u; } t; t.f = f;
  unsigned s = t.u >> 31;
  float a = fabsf(f);
  if (a > 448.f) a = 448.f;
  t.f = a;
  int e = (int)((t.u >> 23) & 0xff) - 127;
  unsigned char r;
  if (a == 0.f) {
    r = 0;
  } else if (e >= -6) {
    unsigned m = t.u & 0x7fffffu;
    unsigned keep = m >> 20, rest = m & 0xfffffu;
    keep += (rest > 0x80000u) || (rest == 0x80000u && (keep & 1u));
    int E = e + 7;
    if (keep == 8u) { keep = 0u; E += 1; }
    if (E >= 16) { E = 15; keep = 6u; }
    r = (unsigned char)((E << 3) | keep);
  } else {
    int mi = (int)(a * 512.f + 0.5f);
    r = (mi > 7) ? (unsigned char)(1u << 3) : (unsigned char)mi;
  }
  return (unsigned char)(r | (s << 7));
#endif
}

// mm from LDS tile: 64 rows x 128 cols, wave = 32r x 64c (B frags hoisted
// inside; used by k_embed which computes its tile in-LDS anyway)
__device__ __forceinline__ void mm_lds_fp8(const unsigned short* sA,
                                           const unsigned short* __restrict__ WT,
                                           int n0, int t,
                                           unsigned char* __restrict__ htOut) {
  int wave = t >> 6, lane = t & 63;
  int wr = wave >> 1, wc = wave & 1;
  int m = lane & 15, quad = (lane >> 4) & 3;
  short8 bh[4][4];
#pragma unroll
  for (int q = 0; q < 4; ++q)
#pragma unroll
    for (int ct = 0; ct < 4; ++ct) {
      int n = wc * 64 + ct * 16 + m;
      bh[q][ct] = *(const short8*)(WT + n * H + q * 32 + quad * 8);
    }
  f32x4 acc[2][4];
#pragma unroll
  for (int i = 0; i < 2; ++i)
#pragma unroll
    for (int j = 0; j < 4; ++j) acc[i][j] = (f32x4){0.f, 0.f, 0.f, 0.f};
#pragma unroll
  for (int q = 0; q < 4; ++q) {
    short8 ah[2];
#pragma unroll
    for (int rt = 0; rt < 2; ++rt)
      ah[rt] = *(const short8*)(sA + (wr * 32 + rt * 16 + m) * 136 + q * 32 + quad * 8);
#pragma unroll
    for (int rt = 0; rt < 2; ++rt)
#pragma unroll
      for (int ct = 0; ct < 4; ++ct)
        acc[rt][ct] = __builtin_amdgcn_mfma_f32_16x16x32_bf16(ah[rt], bh[q][ct], acc[rt][ct], 0, 0, 0);
  }
#pragma unroll
  for (int rt = 0; rt < 2; ++rt)
#pragma unroll
    for (int ct = 0; ct < 4; ++ct) {
      int col = wc * 64 + ct * 16 + m;
#pragma unroll
      for (int rr = 0; rr < 4; ++rr) {
        int gn = n0 + wr * 32 + rt * 16 + quad * 4 + rr;
        if (gn < N_NODES) htOut[(size_t)gn * H + col] = f32_to_fp8(acc[rt][ct][rr]);
      }
    }
}

// ---------------- k_embed: embed 64-node tile -> LDS -> mm W0 ----------------
__global__ __launch_bounds__(256) void k_embed(
    const float* __restrict__ x, const float* __restrict__ W_emb,
    const float* __restrict__ b_emb, unsigned short* __restrict__ h,
    const unsigned short* __restrict__ W0T, unsigned char* __restrict__ ht8) {
  __shared__ __align__(16) char smem[25600];
  int t = threadIdx.x;
  int n0 = blockIdx.x * 64;
  float* sW = (float*)smem;
  float* sX = sW + 4096;
  unsigned short* sH = (unsigned short*)smem;
#pragma unroll
  for (int p = 0; p < 4; ++p)
    ((float4*)sW)[t + p * 256] = ((const float4*)W_emb)[t + p * 256];
#pragma unroll
  for (int p = 0; p < 2; ++p) {
    int fi = t * 2 + p;
    int row = fi >> 3, k4 = (fi & 7) * 4;
    int gn = n0 + row; if (gn >= N_NODES) gn = N_NODES - 1;
    *(float4*)(sX + row * 36 + k4) = *(const float4*)(x + (size_t)gn * F_IN + k4);
  }
  __syncthreads();
  // conflict-free sW reads: col0 = (t&3)*4 -> banks {0,4,8,12}(+16i)
  int nr = t >> 2, col0 = (t & 3) * 4;
  float4 acc[8];
#pragma unroll
  for (int i = 0; i < 8; ++i) acc[i] = make_float4(0.f, 0.f, 0.f, 0.f);
#pragma unroll 4
  for (int k = 0; k < F_IN; ++k) {
    float xv = sX[nr * 36 + k];
    const float* wp = sW + k * H + col0;
#pragma unroll
    for (int i = 0; i < 8; ++i) fma4(acc[i], xv, *(const float4*)(wp + i * 16));
  }
#pragma unroll
  for (int i = 0; i < 8; ++i) {
    float4 bv = *(const float4*)(b_emb + col0 + i * 16);
    acc[i].x += bv.x; acc[i].y += bv.y; acc[i].z += bv.z; acc[i].w += bv.w;
  }
  __syncthreads();  // done reading sW/sX; reuse as sH
  int node = n0 + nr;
  unsigned short* hr = h + (size_t)node * H + col0;
#pragma unroll
  for (int i = 0; i < 8; ++i) {
    st_bf4(sH + nr * 136 + col0 + i * 16, acc[i]);
    if (node < N_NODES) st_bf4(hr + i * 16, acc[i]);
  }
  __syncthreads();
  mm_lds_fp8(sH, W0T, n0, t, ht8);
}

// ---------------- k_p1: bucket-bin edges | k_ws weight prep (fused) --------
__global__ __launch_bounds__(512) void k_p1(const int* __restrict__ ei,
                                            int* __restrict__ bcnt,
                                            unsigned* __restrict__ bscr,
                                            const float* __restrict__ W_conv,
                                            const float* __restrict__ W_res,
                                            unsigned short* __restrict__ whiT) {
  __shared__ int hist[NB];
  __shared__ int hbase[NB];
  int t = threadIdx.x;
  if (blockIdx.x >= P1_BLKS) {            // ---- k_ws role: 40 blocks x 2048
    int base = (blockIdx.x - P1_BLKS) * 2048;
#pragma unroll
    for (int j = 0; j < 4; ++j) {
      int idx = base + j * 512 + t;
      int m = idx >> 14, rr = idx & 16383;
      int k = rr >> 7, n = rr & 127;
      const float* src = (m < 4) ? (W_conv + m * H * H) : W_res;
      whiT[m * H * H + n * H + k] = f2bf(src[k * H + n]);
    }
    return;
  }
  for (int i = t; i < NB; i += 512) hist[i] = 0;
  __syncthreads();
  int e0 = blockIdx.x * P1_EPB;
  unsigned pk[P1_EPT]; int br[P1_EPT];
#pragma unroll
  for (int k = 0; k < P1_EPT; ++k) {
    int e = e0 + k * 512 + t;
    if (e < NEDGES) {
      int src = ei[e];
      int dst = ei[NEDGES + e];
      int b = dst >> 7;
      pk[k] = ((unsigned)src << 7) | (unsigned)(dst & 127);
      int r = atomicAdd(&hist[b], 1);        // DS atomic w/ return
      br[k] = (b << 13) | r;                 // r < 8192 always
    } else {
      br[k] = -1; pk[k] = 0;
    }
  }
  __syncthreads();
  for (int i = t; i < NB; i += 512) {
    int c = hist[i];
    hbase[i] = c ? atomicAdd(&bcnt[i], c) : 0;  // global atomic (sparse)
  }
  __syncthreads();
#pragma unroll
  for (int k = 0; k < P1_EPT; ++k) {
    if (br[k] >= 0) {
      int b = br[k] >> 13, r = br[k] & 8191;
      int pos = hbase[b] + r;
      if (pos < BCAP) bscr[(size_t)b * BCAP + pos] = pk[k];  // safety clamp
    }
  }
}

// ---------------- k_scanbc: exclusive scan of bucket counts ----------------
__global__ void k_scanbc(const int* __restrict__ bcnt, int* __restrict__ bbase) {
  __shared__ int s[1024];
  int t = threadIdx.x;
  int d = (t < NB) ? bcnt[t] : 0;
  s[t] = d;
  __syncthreads();
#pragma unroll
  for (int off = 1; off < 1024; off <<= 1) {
    int v = (t >= off) ? s[t - off] : 0;
    __syncthreads();
    s[t] += v;
    __syncthreads();
  }
  if (t < NB) bbase[t] = s[t] - d;
}

// ---------------- k_p2: per-bucket deg/rank (DS atomics) + csr scatter ------
__global__ __launch_bounds__(256) void k_p2(const unsigned* __restrict__ bscr,
                                            const int* __restrict__ bcnt,
                                            const int* __restrict__ bbase,
                                            int* __restrict__ degT,
                                            int* __restrict__ offs,
                                            float* __restrict__ dinv,
                                            unsigned* __restrict__ csr) {
  __shared__ int dl[128], sc[128];
  int b = blockIdx.x, t = threadIdx.x;
  if (t < 128) dl[t] = 0;
  __syncthreads();
  int n = min(bcnt[b], BCAP);
  int base = bbase[b];
  const unsigned* seg = bscr + (size_t)b * BCAP;
  unsigned pk[P2_IT]; unsigned short rr[P2_IT];
#pragma unroll
  for (int k = 0; k < P2_IT; ++k) {
    int i = k * 256 + t;
    if (i < n) {
      unsigned p = seg[i];
      pk[k] = p;
      rr[k] = (unsigned short)atomicAdd(&dl[p & 127u], 1);
    } else pk[k] = 0xffffffffu;   // payload < 2^24, sentinel safe
  }
  __syncthreads();
  if (t < 128) sc[t] = dl[t];
  __syncthreads();
#pragma unroll
  for (int off = 1; off < 128; off <<= 1) {
    int v = (t >= off && t < 128) ? sc[t - off] : 0;
    __syncthreads();
    if (t < 128) sc[t] += v;
    __syncthreads();
  }
  if (t < 128) {
    int node = b * 128 + t;
    if (node < N_NODES) {
      int d = dl[t];
      degT[node] = d;
      dinv[node] = rsqrtf((float)(d + 1));
      offs[node] = base + sc[t] - d;      // absolute exclusive offset
    }
  }
  __syncthreads();
#pragma unroll
  for (int k = 0; k < P2_IT; ++k) {
    if (pk[k] != 0xffffffffu) {
      unsigned p = pk[k];
      unsigned dlo = p & 127u;
      int pos = base + (sc[dlo] - dl[dlo]) + (int)rr[k];
      csr[pos] = (p >> 7) << 15;          // src<<15; w OR'd in k_wq
    }
  }
}

// ---------------- k_wq: OR quantized dinv[src] into csr entries ------------
__global__ __launch_bounds__(256) void k_wq(unsigned* __restrict__ csr,
                                            const float* __restrict__ dinv) {
  int i = (blockIdx.x * 256 + threadIdx.x) * 4;
  if (i < NEDGES) {
    uint4 e = *(uint4*)(csr + i);
    e.x |= (unsigned)(dinv[e.x >> 15] * 32767.f + 0.5f);
    e.y |= (unsigned)(dinv[e.y >> 15] * 32767.f + 0.5f);
    e.z |= (unsigned)(dinv[e.z >> 15] * 32767.f + 0.5f);
    e.w |= (unsigned)(dinv[e.w >> 15] * 32767.f + 0.5f);
    *(uint4*)(csr + i) = e;
  }
}

// ---------------- k_mm: multi-tile 64x128, B hoisted, reg-prefetch (r21) ----
// r20's per-tile blocks were latency-bound: ~2 blocks/CU resident, ~7us
// block lifetime for ~2us work; B re-loaded by all 1563 blocks. Now each
// block loads B once and loops MMT row-tiles; next tile's A-loads are
// issued right after the barrier and complete under current tile's MFMA.
__global__ __launch_bounds__(256) void k_mm(const unsigned short* __restrict__ A,
                                            const unsigned short* __restrict__ WhiT,
                                            unsigned char* __restrict__ ht8) {
  __shared__ __align__(16) unsigned short sA[64 * 136];
  int t = threadIdx.x;
  int wave = t >> 6, lane = t & 63;
  int wr = wave >> 1, wc = wave & 1;
  int m = lane & 15, quad = (lane >> 4) & 3;
  short8 bh[4][4];
#pragma unroll
  for (int q = 0; q < 4; ++q)
#pragma unroll
    for (int ct = 0; ct < 4; ++ct)
      bh[q][ct] = *(const short8*)(WhiT + (wc * 64 + ct * 16 + m) * H + q * 32 + quad * 8);
  int srow = t >> 4, sc8 = (t & 15) * 8;
  int tbase = blockIdx.x * MMT;
  int nt = min(MMT, TILE_BLKS - tbase);
  uint4 rg[4];
  auto ldA = [&](int n0) {
#pragma unroll
    for (int p = 0; p < 4; ++p) {
      int gn = n0 + srow + 16 * p; if (gn >= N_NODES) gn = N_NODES - 1;
      rg[p] = *(const uint4*)(A + (size_t)gn * H + sc8);
    }
  };
  ldA(tbase * 64);
  for (int tt = 0; tt < nt; ++tt) {
    int n0 = (tbase + tt) * 64;
#pragma unroll
    for (int p = 0; p < 4; ++p)
      *(uint4*)(sA + (srow + 16 * p) * 136 + sc8) = rg[p];
    __syncthreads();
    if (tt + 1 < nt) ldA(n0 + 64);     // prefetch next tile under compute
    f32x4 acc[2][4];
#pragma unroll
    for (int i = 0; i < 2; ++i)
#pragma unroll
      for (int j = 0; j < 4; ++j) acc[i][j] = (f32x4){0.f, 0.f, 0.f, 0.f};
#pragma unroll
    for (int q = 0; q < 4; ++q) {
      short8 ah[2];
#pragma unroll
      for (int rt = 0; rt < 2; ++rt)
        ah[rt] = *(const short8*)(sA + (wr * 32 + rt * 16 + m) * 136 + q * 32 + quad * 8);
#pragma unroll
      for (int rt = 0; rt < 2; ++rt)
#pragma unroll
        for (int ct = 0; ct < 4; ++ct)
          acc[rt][ct] = __builtin_amdgcn_mfma_f32_16x16x32_bf16(ah[rt], bh[q][ct], acc[rt][ct], 0, 0, 0);
    }
#pragma unroll
    for (int rt = 0; rt < 2; ++rt)
#pragma unroll
      for (int ct = 0; ct < 4; ++ct) {
        int col = wc * 64 + ct * 16 + m;
#pragma unroll
        for (int rr = 0; rr < 4; ++rr) {
          int gn = n0 + wr * 32 + rt * 16 + quad * 4 + rr;
          if (gn < N_NODES) ht8[(size_t)gn * H + col] = f32_to_fp8(acc[rt][ct][rr]);
        }
      }
    __syncthreads();                   // all reads of sA done before restage
  }
}

// layer-2 dual GEMM: 64x64 col-half x MMT row-tiles, dual-B hoisted (r21)
__global__ __launch_bounds__(256) void k_mmd(const unsigned short* __restrict__ A,
    const unsigned short* __restrict__ WcT, const unsigned short* __restrict__ WrT,
    const float* __restrict__ bias,
    unsigned char* __restrict__ ht8, unsigned short* __restrict__ resb) {
  __shared__ __align__(16) unsigned short sA[64 * 136];
  int t = threadIdx.x;
  int c0 = (blockIdx.x & 1) * 64;
  int tbase = (blockIdx.x >> 1) * MMT;
  int nt = min(MMT, TILE_BLKS - tbase);
  int wave = t >> 6, lane = t & 63;
  int wr = wave >> 1, wc = wave & 1;
  int m = lane & 15, quad = (lane >> 4) & 3;
  short8 bhc[4][2], bhr[4][2];
#pragma unroll
  for (int q = 0; q < 4; ++q)
#pragma unroll
    for (int ct = 0; ct < 2; ++ct) {
      int n = c0 + wc * 32 + ct * 16 + m;
      bhc[q][ct] = *(const short8*)(WcT + n * H + q * 32 + quad * 8);
      bhr[q][ct] = *(const short8*)(WrT + n * H + q * 32 + quad * 8);
    }
  int srow = t >> 4, sc8 = (t & 15) * 8;
  uint4 rg[4];
  auto ldA = [&](int n0) {
#pragma unroll
    for (int p = 0; p < 4; ++p) {
      int gn = n0 + srow + 16 * p; if (gn >= N_NODES) gn = N_NODES - 1;
      rg[p] = *(const uint4*)(A + (size_t)gn * H + sc8);
    }
  };
  ldA(tbase * 64);
  for (int tt = 0; tt < nt; ++tt) {
    int n0 = (tbase + tt) * 64;
#pragma unroll
    for (int p = 0; p < 4; ++p)
      *(uint4*)(sA + (srow + 16 * p) * 136 + sc8) = rg[p];
    __syncthreads();
    if (tt + 1 < nt) ldA(n0 + 64);
    f32x4 accC[2][2], accR[2][2];
#pragma unroll
    for (int i = 0; i < 2; ++i)
#pragma unroll
      for (int jj = 0; jj < 2; ++jj) {
        accC[i][jj] = (f32x4){0.f, 0.f, 0.f, 0.f};
        accR[i][jj] = (f32x4){0.f, 0.f, 0.f, 0.f};
      }
#pragma unroll
    for (int q = 0; q < 4; ++q) {
      short8 ah[2];
#pragma unroll
      for (int rt = 0; rt < 2; ++rt)
        ah[rt] = *(const short8*)(sA + (wr * 32 + rt * 16 + m) * 136 + q * 32 + quad * 8);
#pragma unroll
      for (int rt = 0; rt < 2; ++rt)
#pragma unroll
        for (int ct = 0; ct < 2; ++ct) {
          accC[rt][ct] = __builtin_amdgcn_mfma_f32_16x16x32_bf16(ah[rt], bhc[q][ct], accC[rt][ct], 0, 0, 0);
          accR[rt][ct] = __builtin_amdgcn_mfma_f32_16x16x32_bf16(ah[rt], bhr[q][ct], accR[rt][ct], 0, 0, 0);
        }
    }
#pragma unroll
    for (int rt = 0; rt < 2; ++rt)
#pragma unroll
      for (int ct = 0; ct < 2; ++ct) {
        int col = c0 + wc * 32 + ct * 16 + m;
        float bv = bias[col];
#pragma unroll
        for (int rr = 0; rr < 4; ++rr) {
          int gn = n0 + wr * 32 + rt * 16 + quad * 4 + rr;
          if (gn < N_NODES) {
            ht8[(size_t)gn * H + col]  = f32_to_fp8(accC[rt][ct][rr]);
            resb[(size_t)gn * H + col] = f2bf(accR[rt][ct][rr] + bv);
          }
        }
      }
    __syncthreads();
  }
}

// ---------------- aggregate(fp8 ht) + bias + LN + relu + residual(bf16) ----
// r18: one node per 16-lane group (4 nodes/wave). r20: branchless 16-deep
// rounds. r21 diagnosis: k_agg is TCC-fill service-bound (~100MB FETCH at
// ~2.95 TB/s == the 43us; ht8 12.8MB > 4MB/XCD L2, random gathers). Parked.
__device__ __forceinline__ void agg_round16(const unsigned char* __restrict__ ht8,
                                            unsigned flo, int gbase,
                                            int s, float w, fv2* acc2) {
  uint2 uu[16]; float ww[16];
#pragma unroll
  for (int jj = 0; jj < 16; ++jj) {
    int ss = __shfl(s, gbase + jj, 64);
    ww[jj] = __shfl(w, gbase + jj, 64);
    uu[jj] = *(const uint2*)(ht8 + (((unsigned)ss << 7) | flo));
  }
#pragma unroll
  for (int jj = 0; jj < 16; ++jj) {
    float we = ww[jj];
    fv2 we2 = {we, we};
    acc2[0] += we2 * fp8x2<false>(uu[jj].x);
    acc2[1] += we2 * fp8x2<true>(uu[jj].x);
    acc2[2] += we2 * fp8x2<false>(uu[jj].y);
    acc2[3] += we2 * fp8x2<true>(uu[jj].y);
  }
}

__global__ __launch_bounds__(512) void k_agg(
    const unsigned char* __restrict__ ht8, const unsigned short* __restrict__ res,
    const float* __restrict__ dinv, const int* __restrict__ offs,
    const int* __restrict__ degT, const unsigned* __restrict__ csr,
    const float* __restrict__ bias, const float* __restrict__ lng,
    const float* __restrict__ lnb, unsigned short* __restrict__ hout) {
  int t = threadIdx.x;
  int fl = t & 15;
  int gbase = t & 48;                    // group base lane within wave
  int node = blockIdx.x * 32 + (t >> 4); // exact: 3125*32 == 100000
  unsigned flo = (unsigned)fl * 8u;
  int start = offs[node], cnt = degT[node];
  float di = dinv[node];
  fv2 acc2[4];
  {
    uint2 u = *(const uint2*)(ht8 + (((unsigned)node << 7) | flo));
    float sw = di * di;
    fv2 sw2 = {sw, sw};
    acc2[0] = sw2 * fp8x2<false>(u.x);
    acc2[1] = sw2 * fp8x2<true>(u.x);
    acc2[2] = sw2 * fp8x2<false>(u.y);
    acc2[3] = sw2 * fp8x2<true>(u.y);
  }
  float ddq = di * (1.f / 32767.f);
  for (int b0 = 0; b0 < cnt; b0 += 16) {
    int s = node; float w = 0.f;
    if (b0 + fl < cnt) {
      unsigned ev = csr[start + b0 + fl];
      s = (int)(ev >> 15);
      w = (float)(ev & 32767u) * ddq;
    }
    agg_round16(ht8, flo, gbase, s, w, acc2);
  }
  float acc[8] = {acc2[0].x, acc2[0].y, acc2[1].x, acc2[1].y,
                  acc2[2].x, acc2[2].y, acc2[3].x, acc2[3].y};
  float4 b0v = *(const float4*)(bias + fl * 8);
  float4 b1v = *(const float4*)(bias + fl * 8 + 4);
  acc[0] += b0v.x; acc[1] += b0v.y; acc[2] += b0v.z; acc[3] += b0v.w;
  acc[4] += b1v.x; acc[5] += b1v.y; acc[6] += b1v.z; acc[7] += b1v.w;
  float sl = ((acc[0] + acc[1]) + (acc[2] + acc[3])) +
             ((acc[4] + acc[5]) + (acc[6] + acc[7]));
#pragma unroll
  for (int mk = 1; mk <= 8; mk <<= 1) sl += __shfl_xor(sl, mk, 16);
  float mu = sl * (1.f / 128.f);
  float d[8];
  float vl = 0.f;
#pragma unroll
  for (int j = 0; j < 8; ++j) { d[j] = acc[j] - mu; vl = fmaf(d[j], d[j], vl); }
#pragma unroll
  for (int mk = 1; mk <= 8; mk <<= 1) vl += __shfl_xor(vl, mk, 16);
  float rs = rsqrtf(vl * (1.f / 128.f) + EPS);
  float4 g0 = *(const float4*)(lng + fl * 8);
  float4 g1 = *(const float4*)(lng + fl * 8 + 4);
  float4 be0 = *(const float4*)(lnb + fl * 8);
  float4 be1 = *(const float4*)(lnb + fl * 8 + 4);
  uint4 rv = *(const uint4*)(res + (size_t)node * 128 + fl * 8);
  float o0 = fmaxf(fmaf(d[0] * rs, g0.x, be0.x), 0.f) + bflo(rv.x);
  float o1 = fmaxf(fmaf(d[1] * rs, g0.y, be0.y), 0.f) + bfhi(rv.x);
  float o2 = fmaxf(fmaf(d[2] * rs, g0.z, be0.z), 0.f) + bflo(rv.y);
  float o3 = fmaxf(fmaf(d[3] * rs, g0.w, be0.w), 0.f) + bfhi(rv.y);
  float o4 = fmaxf(fmaf(d[4] * rs, g1.x, be1.x), 0.f) + bflo(rv.z);
  float o5 = fmaxf(fmaf(d[5] * rs, g1.y, be1.y), 0.f) + bfhi(rv.z);
  float o6 = fmaxf(fmaf(d[6] * rs, g1.z, be1.z), 0.f) + bflo(rv.w);
  float o7 = fmaxf(fmaf(d[7] * rs, g1.w, be1.w), 0.f) + bfhi(rv.w);
  uint4 ov;
  ov.x = pack2(o0, o1); ov.y = pack2(o2, o3);
  ov.z = pack2(o4, o5); ov.w = pack2(o6, o7);
  *(uint4*)(hout + (size_t)node * 128 + fl * 8) = ov;
}

// ---------------- mean pool (bf16 h, vectorized uint4 loads) ----------------
__global__ __launch_bounds__(256) void k_pool(const unsigned short* __restrict__ h,
                                              float* __restrict__ pool) {
  __shared__ float colsum[128];
  int t = threadIdx.x;
  if (t < 128) colsum[t] = 0.f;
  __syncthreads();
  int lr = t >> 4, seg = t & 15;   // 16 rows/pass, 16 x uint4 per row
  float acc[8] = {0.f, 0.f, 0.f, 0.f, 0.f, 0.f, 0.f, 0.f};
  for (int n = blockIdx.x * 16 + lr; n < N_NODES; n += gridDim.x * 16) {
    uint4 u = *(const uint4*)(h + (size_t)n * H + seg * 8);
    acc[0] += bflo(u.x); acc[1] += bfhi(u.x);
    acc[2] += bflo(u.y); acc[3] += bfhi(u.y);
    acc[4] += bflo(u.z); acc[5] += bfhi(u.z);
    acc[6] += bflo(u.w); acc[7] += bfhi(u.w);
  }
#pragma unroll
  for (int j = 0; j < 8; ++j) atomicAdd(&colsum[seg * 8 + j], acc[j]);
  __syncthreads();
  if (t < 128) atomicAdd(&pool[t], colsum[t]);
}

// ---------------- head ----------------
__global__ void k_head(const float* __restrict__ pool, const float* __restrict__ Wfc1,
                       const float* __restrict__ bfc1, const float* __restrict__ g,
                       const float* __restrict__ bb, const float* __restrict__ Wfc2,
                       const float* __restrict__ bfc2, float* __restrict__ out) {
  __shared__ float sm[128], s1[128], stats[2];
  int t = threadIdx.x;
  if (t < 128) sm[t] = pool[t] * (1.f / (float)N_NODES);
  __syncthreads();
  if (t < 128) {
    float a = bfc1[t];
    for (int k = 0; k < 128; ++k) a = fmaf(sm[k], Wfc1[k * 128 + t], a);
    s1[t] = a;
  }
  __syncthreads();
  if (t == 0) {
    float mu = 0.f;
    for (int k = 0; k < 128; ++k) mu += s1[k];
    mu *= (1.f / 128.f);
    float var = 0.f;
    for (int k = 0; k < 128; ++k) { float d = s1[k] - mu; var += d * d; }
    var *= (1.f / 128.f);
    stats[0] = mu; stats[1] = rsqrtf(var + EPS);
  }
  __syncthreads();
  if (t < 128) s1[t] = fmaxf((s1[t] - stats[0]) * stats[1] * g[t] + bb[t], 0.f);
  __syncthreads();
  if (t < OUT_F) {
    float a = bfc2[t];
    for (int k = 0; k < 128; ++k) a = fmaf(s1[k], Wfc2[k * OUT_F + t], a);
    out[t] = a;
  }
}

extern "C" void kernel_launch(void* const* d_in, const int* in_sizes, int n_in,
                              void* d_out, int out_size, void* d_ws, size_t ws_size,
                              hipStream_t stream) {
  const float* x      = (const float*)d_in[0];
  const int*   ei     = (const int*)d_in[1];
  const float* W_emb  = (const float*)d_in[2];
  const float* b_emb  = (const float*)d_in[3];
  const float* W_conv = (const float*)d_in[4];
  const float* b_conv = (const float*)d_in[5];
  const float* ln_g   = (const float*)d_in[6];
  const float* ln_b   = (const float*)d_in[7];
  const float* W_res  = (const float*)d_in[8];
  const float* b_res  = (const float*)d_in[9];
  const float* W_fc1  = (const float*)d_in[10];
  const float* b_fc1  = (const float*)d_in[11];
  const float* fcn_g  = (const float*)d_in[12];
  const float* fcn_b  = (const float*)d_in[13];
  const float* W_fc2  = (const float*)d_in[14];
  const float* b_fc2  = (const float*)d_in[15];
  float* out = (float*)d_out;

  char* p = (char*)d_ws;
  auto take = [&](size_t bytes) {
    char* r = p; p += (bytes + 255) & ~(size_t)255; return r;
  };
  unsigned short* bufA = (unsigned short*)take((size_t)N_NODES * H * 2);
  unsigned short* bufB = (unsigned short*)take((size_t)N_NODES * H * 2);
  unsigned short* bufC = (unsigned short*)take((size_t)N_NODES * H * 2);
  unsigned char*  ht8  = (unsigned char*)take((size_t)N_NODES * H);
  unsigned short* whiT = (unsigned short*)take((size_t)5 * H * H * 2);
  int*   degT = (int*)take(N_NODES * 4);
  int*   offs = (int*)take(N_NODES * 4);
  float* dinv = (float*)take(N_NODES * 4);
  int*   bcnt = (int*)take(NB * 4);
  int*   bbase= (int*)take(NB * 4);
  unsigned* bscr = (unsigned*)take((size_t)NB * BCAP * 4);
  unsigned* csr  = (unsigned*)take((size_t)NEDGES * 4);
  float* pool = (float*)take(128 * 4);

  (void)hipMemsetAsync(bcnt, 0, NB * 4, stream);
  (void)hipMemsetAsync(pool, 0, 128 * 4, stream);

  k_p1<<<P1_BLKS + WS_BLKS, P1_THR, 0, stream>>>(ei, bcnt, bscr,
                                                 W_conv, W_res, whiT);
  k_scanbc<<<1, 1024, 0, stream>>>(bcnt, bbase);
  k_p2<<<NB, 256, 0, stream>>>(bscr, bcnt, bbase, degT, offs, dinv, csr);
  k_wq<<<WQ_BLKS, 256, 0, stream>>>(csr, dinv);
  k_embed<<<TILE_BLKS, 256, 0, stream>>>(x, W_emb, b_emb, bufA,
                                         whiT + 0 * H * H, ht8);

  // L0: res=h0=A -> h1=C
  k_agg<<<AGG_BLKS, 512, 0, stream>>>(ht8, bufA, dinv, offs, degT, csr,
                                      b_conv + 0 * H, ln_g + 0 * H, ln_b + 0 * H, bufC);
  // L1: h1=C -> ht8 -> h2=A (res=C)
  k_mm<<<MM_BLKS, 256, 0, stream>>>(bufC, whiT + 1 * H * H, ht8);
  k_agg<<<AGG_BLKS, 512, 0, stream>>>(ht8, bufC, dinv, offs, degT, csr,
                                      b_conv + 1 * H, ln_g + 1 * H, ln_b + 1 * H, bufA);
  // L2: h2=A; dual: ht8=A@W2, B=bf16(A@Wres+bres); agg -> h3=C (res=B)
  k_mmd<<<MMD_BLKS, 256, 0, stream>>>(bufA, whiT + 2 * H * H, whiT + 4 * H * H,
                                      b_res, ht8, bufB);
  k_agg<<<AGG_BLKS, 512, 0, stream>>>(ht8, bufB, dinv, offs, degT, csr,
                                      b_conv + 2 * H, ln_g + 2 * H, ln_b + 2 * H, bufC);
  // L3: h3=C -> ht8 -> h4=A (res=C)
  k_mm<<<MM_BLKS, 256, 0, stream>>>(bufC, whiT + 3 * H * H, ht8);
  k_agg<<<AGG_BLKS, 512, 0, stream>>>(ht8, bufC, dinv, offs, degT, csr,
                                      b_conv + 3 * H, ln_g + 3 * H, ln_b + 3 * H, bufA);

  k_pool<<<256, 256, 0, stream>>>(bufA, pool);
  k_head<<<1, 256, 0, stream>>>(pool, W_fc1, b_fc1, fcn_g, fcn_b,
                                W_fc2, b_fc2, out);
}